// Round 3
// baseline (968.575 us; speedup 1.0000x reference)
//
#include <hip/hip_runtime.h>
#include <math.h>

// GConvLSTM fused, fp32. ChebConv K=1 => edge_index/edge_weight never read.
// R2: weights via uniform s_load (SGPR operand FMAs), zero LDS in hot kernel.
// Outputs concatenated: y [N,9] | h0 [N,32] | c0 [N,32]

#define HD 32
#define FD 8
#define BLK 256

// float offsets into the packed constant block in d_ws
#define CW_WXT 0        // [4][32][8]  transposed Wx
#define CW_WHT 1024     // [4][32][32] transposed Wh
#define CW_WL  5120     // [32][12]    Wl rows padded to 12
#define CW_B   5504     // [4][32]     bx+bh+b merged
#define CW_PCI 5632     // [32] wci
#define CW_PCF 5664     // [32] wcf
#define CW_PCO 5696     // [32] wco
#define CW_BL  5728     // [12] bl padded
#define CW_TOT 5740

struct PrepArgs {
    const float* Wxi; const float* Wxf; const float* Wxc; const float* Wxo;
    const float* Whi; const float* Whf; const float* Whc; const float* Who;
    const float* bxi; const float* bxf; const float* bxc; const float* bxo;
    const float* bhi; const float* bhf; const float* bhc; const float* bho;
    const float* bi;  const float* bf;  const float* bc;  const float* bo;
    const float* wci; const float* wcf; const float* wco;
    const float* Wl;  const float* bl;
};

__global__ __launch_bounds__(256) void prep_kernel(PrepArgs a, float* __restrict__ w) {
    const int t = threadIdx.x;
    // WXT[g][j][k] = Wx_g[k][j]; all gate pointers compile-time (no dynamic ptr-array idx)
#define DO_WX(G, PTR)                                                     \
    for (int i = t; i < HD * FD; i += 256) {                              \
        int j = i >> 3, k = i & 7;                                        \
        w[CW_WXT + (G) * HD * FD + i] = PTR[k * HD + j];                  \
    }
    DO_WX(0, a.Wxi) DO_WX(1, a.Wxf) DO_WX(2, a.Wxc) DO_WX(3, a.Wxo)
#undef DO_WX
#define DO_WH(G, PTR)                                                     \
    for (int i = t; i < HD * HD; i += 256) {                              \
        int j = i >> 5, k = i & 31;                                       \
        w[CW_WHT + (G) * HD * HD + i] = PTR[k * HD + j];                  \
    }
    DO_WH(0, a.Whi) DO_WH(1, a.Whf) DO_WH(2, a.Whc) DO_WH(3, a.Who)
#undef DO_WH
    for (int i = t; i < HD * 12; i += 256) {
        int j = i / 12, m = i - j * 12;
        w[CW_WL + i] = (m < 9) ? a.Wl[j * 9 + m] : 0.0f;
    }
#define DO_B(G, P1, P2, P3)                                               \
    for (int i = t; i < HD; i += 256) {                                   \
        w[CW_B + (G) * HD + i] = P1[i] + P2[i] + P3[i];                   \
    }
    DO_B(0, a.bxi, a.bhi, a.bi) DO_B(1, a.bxf, a.bhf, a.bf)
    DO_B(2, a.bxc, a.bhc, a.bc) DO_B(3, a.bxo, a.bho, a.bo)
#undef DO_B
    if (t < HD) {
        w[CW_PCI + t] = a.wci[t];
        w[CW_PCF + t] = a.wcf[t];
        w[CW_PCO + t] = a.wco[t];
    }
    if (t < 12) w[CW_BL + t] = (t < 9) ? a.bl[t] : 0.0f;
}

__device__ __forceinline__ float rcp_f(float v) { return __builtin_amdgcn_rcpf(v); }
__device__ __forceinline__ float fsigmoid(float v) { return rcp_f(1.0f + __expf(-v)); }
__device__ __forceinline__ float ftanh(float v) {
    // tanh(x) = 2*sigmoid(2x)-1; overflow-safe both directions (exp->inf -> rcp->0 -> -1)
    return __builtin_fmaf(2.0f, rcp_f(1.0f + __expf(-2.0f * v)), -1.0f);
}

__global__ __launch_bounds__(BLK) void gconvlstm_main(
    const float* __restrict__ x, const float* __restrict__ h, const float* __restrict__ c,
    const float* __restrict__ cw,
    float* __restrict__ y, float* __restrict__ h0, float* __restrict__ c0, int N)
{
    const int n = blockIdx.x * BLK + threadIdx.x;
    if (n >= N) return;

    float xv[FD];
    {
        const float4* xp = reinterpret_cast<const float4*>(x + (size_t)n * FD);
        reinterpret_cast<float4*>(xv)[0] = xp[0];
        reinterpret_cast<float4*>(xv)[1] = xp[1];
    }
    float hv[HD];
    {
        const float4* hp = reinterpret_cast<const float4*>(h + (size_t)n * HD);
#pragma unroll
        for (int q = 0; q < 8; ++q) reinterpret_cast<float4*>(hv)[q] = hp[q];
    }

    float yacc[9];
#pragma unroll
    for (int m = 0; m < 9; ++m) yacc[m] = cw[CW_BL + m];   // uniform -> s_load

    const float4* cp  = reinterpret_cast<const float4*>(c  + (size_t)n * HD);
    float4*       hop = reinterpret_cast<float4*>(h0 + (size_t)n * HD);
    float4*       cop = reinterpret_cast<float4*>(c0 + (size_t)n * HD);

    // j in chunks of 4: keeps live VGPRs low and the loop body ~I$-sized.
    // jc is uniform -> every cw[] address below is uniform -> SMEM (s_load).
#pragma unroll 1
    for (int jc = 0; jc < 8; ++jc) {
        const float4 c4 = cp[jc];
        float h04[4], c04[4];
#pragma unroll
        for (int jj = 0; jj < 4; ++jj) {
            const int j = jc * 4 + jj;
            float ag[4];
#pragma unroll
            for (int g = 0; g < 4; ++g) {
                float acc = cw[CW_B + g * HD + j];
                const float* __restrict__ wx = cw + CW_WXT + (g * HD + j) * FD;
#pragma unroll
                for (int k = 0; k < FD; ++k) acc += xv[k] * wx[k];
                const float* __restrict__ wh = cw + CW_WHT + (g * HD + j) * HD;
#pragma unroll
                for (int k = 0; k < HD; ++k) acc += hv[k] * wh[k];
                ag[g] = acc;
            }
            const float cj = (&c4.x)[jj];
            const float ig = fsigmoid(ag[0] + cw[CW_PCI + j] * cj);
            const float fg = fsigmoid(ag[1] + cw[CW_PCF + j] * cj);
            const float tg = ftanh(ag[2]);
            const float cn = fg * cj + ig * tg;
            const float og = fsigmoid(ag[3] + cw[CW_PCO + j] * cn);
            const float hn = og * ftanh(cn);
            c04[jj] = cn;
            h04[jj] = hn;
            const float rh = fmaxf(hn, 0.0f);
            const float* __restrict__ wl = cw + CW_WL + j * 12;
#pragma unroll
            for (int m = 0; m < 9; ++m) yacc[m] += rh * wl[m];
        }
        hop[jc] = make_float4(h04[0], h04[1], h04[2], h04[3]);
        cop[jc] = make_float4(c04[0], c04[1], c04[2], c04[3]);
    }

    float* yo = y + (size_t)n * 9;
#pragma unroll
    for (int m = 0; m < 9; ++m) yo[m] = yacc[m];
}

extern "C" void kernel_launch(void* const* d_in, const int* in_sizes, int n_in,
                              void* d_out, int out_size, void* d_ws, size_t ws_size,
                              hipStream_t stream) {
    (void)n_in; (void)out_size; (void)ws_size;
    const int N = in_sizes[0] / FD;   // x is [N,8]

    PrepArgs a;
    a.Wxi = (const float*)d_in[5];  a.bxi = (const float*)d_in[6];
    a.Whi = (const float*)d_in[7];  a.bhi = (const float*)d_in[8];
    a.bi  = (const float*)d_in[9];  a.wci = (const float*)d_in[10];
    a.Wxf = (const float*)d_in[11]; a.bxf = (const float*)d_in[12];
    a.Whf = (const float*)d_in[13]; a.bhf = (const float*)d_in[14];
    a.bf  = (const float*)d_in[15]; a.wcf = (const float*)d_in[16];
    a.Wxc = (const float*)d_in[17]; a.bxc = (const float*)d_in[18];
    a.Whc = (const float*)d_in[19]; a.bhc = (const float*)d_in[20];
    a.bc  = (const float*)d_in[21];
    a.Wxo = (const float*)d_in[22]; a.bxo = (const float*)d_in[23];
    a.Who = (const float*)d_in[24]; a.bho = (const float*)d_in[25];
    a.bo  = (const float*)d_in[26]; a.wco = (const float*)d_in[27];
    a.Wl  = (const float*)d_in[28]; a.bl  = (const float*)d_in[29];

    float* ws = (float*)d_ws;
    prep_kernel<<<1, 256, 0, stream>>>(a, ws);

    float* out = (float*)d_out;
    const int blocks = (N + BLK - 1) / BLK;
    gconvlstm_main<<<blocks, BLK, 0, stream>>>(
        (const float*)d_in[0], (const float*)d_in[3], (const float*)d_in[4],
        ws,
        out, out + (size_t)9 * N, out + (size_t)41 * N, N);
}

// Round 5
// 910.754 us; speedup vs baseline: 1.0635x; 1.0635x over previous
//
#include <hip/hip_runtime.h>
#include <math.h>

// GConvLSTM fused, fp32. ChebConv K=1 => edge_index/edge_weight never read.
// R4: s_load (SGPR-operand) weights + R1's bulk I/O pattern:
//   - all per-node loads up front (contiguous float4), all stores at the end
//     back-to-back (full 128B lines -> no read-for-ownership / L2 thrash; this
//     was R3's 2.6x HBM-traffic regression).
//   - weights packed [j][gate][40] sequentially so fully-unrolled j-loop reads
//     them with merged s_load_dwordx16 (scalar K$ broadcast; zero LDS, zero
//     per-lane operand bandwidth -- R1's 20GB LDS-read floor eliminated).
// Outputs concatenated: y [N,9] | h0 [N,32] | c0 [N,32]

#define HD 32
#define FD 8
#define BLK 256

// float offsets into packed constant block in d_ws
#define CW_W40 0        // [32][4][40]  row j,gate g: [x-weights(8) | h-weights(32)]
#define CW_WL  5120     // [32][12]     Wl rows padded to 12
#define CW_SCV 5504     // [32][8]      per-j: Bi,Bf,Bc,Bo (bx+bh+b), wci,wcf,wco,0
#define CW_BL  5760     // [12]         bl padded
#define CW_TOT 5772

struct PrepArgs {
    const float* Wxi; const float* Wxf; const float* Wxc; const float* Wxo;
    const float* Whi; const float* Whf; const float* Whc; const float* Who;
    const float* bxi; const float* bxf; const float* bxc; const float* bxo;
    const float* bhi; const float* bhf; const float* bhc; const float* bho;
    const float* bi;  const float* bf;  const float* bc;  const float* bo;
    const float* wci; const float* wcf; const float* wco;
    const float* Wl;  const float* bl;
};

__global__ __launch_bounds__(256) void prep_kernel(PrepArgs a, float* __restrict__ w) {
    const int t = threadIdx.x;
    // W40[j][g][k]: k<8 -> Wx_g[k][j], k>=8 -> Wh_g[k-8][j]
#define DO_W(G, PX, PH)                                                   \
    for (int i = t; i < HD * 40; i += 256) {                              \
        int j = i / 40, k = i - j * 40;                                   \
        float v = (k < FD) ? PX[k * HD + j] : PH[(k - FD) * HD + j];      \
        w[CW_W40 + (j * 4 + (G)) * 40 + k] = v;                           \
    }
    DO_W(0, a.Wxi, a.Whi) DO_W(1, a.Wxf, a.Whf)
    DO_W(2, a.Wxc, a.Whc) DO_W(3, a.Wxo, a.Who)
#undef DO_W
    for (int i = t; i < HD * 12; i += 256) {
        int j = i / 12, m = i - j * 12;
        w[CW_WL + i] = (m < 9) ? a.Wl[j * 9 + m] : 0.0f;
    }
    for (int i = t; i < HD * 8; i += 256) {
        int j = i >> 3, s = i & 7;
        float v = 0.0f;
        switch (s) {
            case 0: v = a.bxi[j] + a.bhi[j] + a.bi[j]; break;
            case 1: v = a.bxf[j] + a.bhf[j] + a.bf[j]; break;
            case 2: v = a.bxc[j] + a.bhc[j] + a.bc[j]; break;
            case 3: v = a.bxo[j] + a.bho[j] + a.bo[j]; break;
            case 4: v = a.wci[j]; break;
            case 5: v = a.wcf[j]; break;
            case 6: v = a.wco[j]; break;
            default: v = 0.0f;
        }
        w[CW_SCV + i] = v;
    }
    if (t < 12) w[CW_BL + t] = (t < 9) ? a.bl[t] : 0.0f;
}

__device__ __forceinline__ float rcp_f(float v) { return __builtin_amdgcn_rcpf(v); }
__device__ __forceinline__ float fsigmoid(float v) { return rcp_f(1.0f + __expf(-v)); }
__device__ __forceinline__ float ftanh(float v) {
    // tanh(x) = 2*sigmoid(2x)-1; overflow-safe both directions (exp->inf -> rcp->0 -> -1)
    return __builtin_fmaf(2.0f, rcp_f(1.0f + __expf(-2.0f * v)), -1.0f);
}

__global__ __launch_bounds__(BLK) void gconvlstm_main(
    const float* __restrict__ x, const float* __restrict__ h, const float* __restrict__ c,
    const float* __restrict__ cw,
    float* __restrict__ y, float* __restrict__ h0, float* __restrict__ c0, int N)
{
    const int n = blockIdx.x * BLK + threadIdx.x;
    if (n >= N) return;

    // ---- bulk loads up front (contiguous, coalesced) ----
    float av[40];                       // [x(8) | h(32)]
    {
        const float4* xp = reinterpret_cast<const float4*>(x + (size_t)n * FD);
        reinterpret_cast<float4*>(av)[0] = xp[0];
        reinterpret_cast<float4*>(av)[1] = xp[1];
        const float4* hp = reinterpret_cast<const float4*>(h + (size_t)n * HD);
#pragma unroll
        for (int q = 0; q < 8; ++q) reinterpret_cast<float4*>(av + FD)[q] = hp[q];
    }
    float cv[HD];                       // becomes c0 in place
    {
        const float4* cp = reinterpret_cast<const float4*>(c + (size_t)n * HD);
#pragma unroll
        for (int q = 0; q < 8; ++q) reinterpret_cast<float4*>(cv)[q] = cp[q];
    }
    float h0a[HD];
    float yacc[9];
#pragma unroll
    for (int m = 0; m < 9; ++m) yacc[m] = cw[CW_BL + m];   // uniform -> s_load

    // ---- fully unrolled: every cw[] offset is compile-time -> s_load ----
#pragma unroll
    for (int j = 0; j < HD; ++j) {
        const float* __restrict__ wr = cw + CW_W40 + j * 160;
        const float* __restrict__ sc = cw + CW_SCV + j * 8;
        float ai = sc[0], af = sc[1], at = sc[2], ao = sc[3];
#pragma unroll
        for (int k = 0; k < 40; ++k) {
            const float a = av[k];
            ai += a * wr[k];
            af += a * wr[40 + k];
            at += a * wr[80 + k];
            ao += a * wr[120 + k];
        }
        const float cj = cv[j];
        const float ig = fsigmoid(ai + sc[4] * cj);
        const float fg = fsigmoid(af + sc[5] * cj);
        const float tg = ftanh(at);
        const float cn = fg * cj + ig * tg;
        const float og = fsigmoid(ao + sc[6] * cn);
        const float hn = og * ftanh(cn);
        cv[j]  = cn;
        h0a[j] = hn;
        const float rh = fmaxf(hn, 0.0f);
        const float* __restrict__ wl = cw + CW_WL + j * 12;
#pragma unroll
        for (int m = 0; m < 9; ++m) yacc[m] += rh * wl[m];
    }

    // ---- bulk stores, back-to-back (full-line coalescing) ----
    float* yo = y + (size_t)n * 9;
#pragma unroll
    for (int m = 0; m < 9; ++m) yo[m] = yacc[m];
    float4* hop = reinterpret_cast<float4*>(h0 + (size_t)n * HD);
#pragma unroll
    for (int q = 0; q < 8; ++q) hop[q] = reinterpret_cast<const float4*>(h0a)[q];
    float4* cop = reinterpret_cast<float4*>(c0 + (size_t)n * HD);
#pragma unroll
    for (int q = 0; q < 8; ++q) cop[q] = reinterpret_cast<const float4*>(cv)[q];
}

extern "C" void kernel_launch(void* const* d_in, const int* in_sizes, int n_in,
                              void* d_out, int out_size, void* d_ws, size_t ws_size,
                              hipStream_t stream) {
    (void)n_in; (void)out_size; (void)ws_size;
    const int N = in_sizes[0] / FD;   // x is [N,8]

    PrepArgs a;
    a.Wxi = (const float*)d_in[5];  a.bxi = (const float*)d_in[6];
    a.Whi = (const float*)d_in[7];  a.bhi = (const float*)d_in[8];
    a.bi  = (const float*)d_in[9];  a.wci = (const float*)d_in[10];
    a.Wxf = (const float*)d_in[11]; a.bxf = (const float*)d_in[12];
    a.Whf = (const float*)d_in[13]; a.bhf = (const float*)d_in[14];
    a.bf  = (const float*)d_in[15]; a.wcf = (const float*)d_in[16];
    a.Wxc = (const float*)d_in[17]; a.bxc = (const float*)d_in[18];
    a.Whc = (const float*)d_in[19]; a.bhc = (const float*)d_in[20];
    a.bc  = (const float*)d_in[21];
    a.Wxo = (const float*)d_in[22]; a.bxo = (const float*)d_in[23];
    a.Who = (const float*)d_in[24]; a.bho = (const float*)d_in[25];
    a.bo  = (const float*)d_in[26]; a.wco = (const float*)d_in[27];
    a.Wl  = (const float*)d_in[28]; a.bl  = (const float*)d_in[29];

    float* ws = (float*)d_ws;
    prep_kernel<<<1, 256, 0, stream>>>(a, ws);

    float* out = (float*)d_out;
    const int blocks = (N + BLK - 1) / BLK;
    gconvlstm_main<<<blocks, BLK, 0, stream>>>(
        (const float*)d_in[0], (const float*)d_in[3], (const float*)d_in[4],
        ws,
        out, out + (size_t)9 * N, out + (size_t)41 * N, N);
}